// Round 2
// baseline (62.653 us; speedup 1.0000x reference)
//
#include <hip/hip_runtime.h>

// VirtualValueNetwork: out[b,i] = min_k max_j (bids[b,i]*exp(w[i,k,j]) + beta[i,k,j])
// B=16384, N=1024, K=2, J=3.
// R3: R2 minus the nontemporal hints (they broke TCC servicing of the read
// stream: FETCH_SIZE halved, BW fell to 2.4 TB/s, kernel went latency-bound).
// Keep the float4 16B/lane streams; restore launch_bounds(256,8) since
// VGPR_Count=44 allows full 8 waves/SIMD.

typedef float f4 __attribute__((ext_vector_type(4)));

#define NB    1024
#define BATCH 16384
#define KK    2
#define JJ    3
#define ROWS  4            // rows per block; grid = 16384/4 = 4096 blocks

__global__ __launch_bounds__(256, 8) void vvn_kernel(
    const float* __restrict__ bids,
    const float* __restrict__ w,
    const float* __restrict__ beta,
    float* __restrict__ out)
{
    const int t  = threadIdx.x;        // 0..255
    const int i0 = t << 2;             // 4 consecutive buyers per thread
    const size_t base = (size_t)blockIdx.x * ROWS * NB + i0;

    // --- Issue the HBM stream loads FIRST: 4 x global_load_dwordx4 ---
    f4 bv[ROWS];
#pragma unroll
    for (int r = 0; r < ROWS; ++r) {
        bv[r] = *reinterpret_cast<const f4*>(&bids[base + (size_t)r * NB]);
    }

    // --- Params for 4 buyers: 24 consecutive floats each (96 B, 16B-aligned,
    // coalesced dwordx4; 48 KiB total -> L2-hot). Loaded and exp'd while the
    // bids loads are in flight. ---
    f4 wv[6], bb[6];
    {
        const f4* wp = reinterpret_cast<const f4*>(w    + (size_t)i0 * (KK * JJ));
        const f4* bp = reinterpret_cast<const f4*>(beta + (size_t)i0 * (KK * JJ));
#pragma unroll
        for (int q = 0; q < 6; ++q) { wv[q] = wp[q]; bb[q] = bp[q]; }
    }

    float ew[4][KK][JJ];
    float bt[4][KK][JJ];
#pragma unroll
    for (int u = 0; u < 4; ++u) {
#pragma unroll
        for (int k = 0; k < KK; ++k) {
#pragma unroll
            for (int j = 0; j < JJ; ++j) {
                const int idx = u * (KK * JJ) + k * JJ + j;  // compile-time after unroll
                ew[u][k][j] = __expf(reinterpret_cast<const float*>(wv)[idx]);
                bt[u][k][j] = reinterpret_cast<const float*>(bb)[idx];
            }
        }
    }

#pragma unroll
    for (int r = 0; r < ROWS; ++r) {
        f4 res;
#pragma unroll
        for (int u = 0; u < 4; ++u) {
            const float a = bv[r][u];
            float m0 = fmaf(a, ew[u][0][0], bt[u][0][0]);
            m0 = fmaxf(m0, fmaf(a, ew[u][0][1], bt[u][0][1]));
            m0 = fmaxf(m0, fmaf(a, ew[u][0][2], bt[u][0][2]));
            float m1 = fmaf(a, ew[u][1][0], bt[u][1][0]);
            m1 = fmaxf(m1, fmaf(a, ew[u][1][1], bt[u][1][1]));
            m1 = fmaxf(m1, fmaf(a, ew[u][1][2], bt[u][1][2]));
            res[u] = fminf(m0, m1);
        }
        *reinterpret_cast<f4*>(&out[base + (size_t)r * NB]) = res;
    }
}

extern "C" void kernel_launch(void* const* d_in, const int* in_sizes, int n_in,
                              void* d_out, int out_size, void* d_ws, size_t ws_size,
                              hipStream_t stream) {
    const float* bids = (const float*)d_in[0];   // [16384, 1024]
    const float* w    = (const float*)d_in[1];   // [1024, 2, 3]
    const float* beta = (const float*)d_in[2];   // [1024, 2, 3]
    float* out = (float*)d_out;                  // [16384, 1024]

    vvn_kernel<<<dim3(BATCH / ROWS), dim3(256), 0, stream>>>(bids, w, beta, out);
}

// Round 3
// 29.126 us; speedup vs baseline: 2.1511x; 2.1511x over previous
//
#include <hip/hip_runtime.h>

// VirtualValueNetwork: out[b,i] = min_k max_j (bids[b,i]*exp(w[i,k,j]) + beta[i,k,j])
// B=16384, N=1024, K=2, J=3.
// R4: first CLEAN test of float4 streams.
//  - R2 failed: nontemporal hints broke TCC servicing + compiler sank the row
//    loads (VGPR 44 < live set ==> restructured schedule).
//  - R3 failed: launch_bounds(256,8) capped VGPR at 64 < ~75 live ==> params
//    spilled to scratch (WRITE_SIZE 64->184 MiB).
//  Fixes: launch_bounds(256,4) (cap 128, no spill; 16 waves/CU is plenty for
//  BW), no nt, and sched_barrier(0) after issuing ALL loads so the scheduler
//  cannot sink them below the exp/compute.

typedef float f4 __attribute__((ext_vector_type(4)));

#define NB    1024
#define BATCH 16384
#define KK    2
#define JJ    3
#define ROWS  4            // rows per block; grid = 16384/4 = 4096 blocks

__global__ __launch_bounds__(256, 4) void vvn_kernel(
    const float* __restrict__ bids,
    const float* __restrict__ w,
    const float* __restrict__ beta,
    float* __restrict__ out)
{
    const int t  = threadIdx.x;        // 0..255
    const int i0 = t << 2;             // 4 consecutive buyers per thread
    const size_t base = (size_t)blockIdx.x * ROWS * NB + i0;

    // --- Issue ALL loads first: 4x dwordx4 (HBM stream) + 6x dwordx4 (L2 params)
    f4 bv[ROWS];
#pragma unroll
    for (int r = 0; r < ROWS; ++r) {
        bv[r] = *reinterpret_cast<const f4*>(&bids[base + (size_t)r * NB]);
    }

    f4 wv[6], bb[6];
    {
        const f4* wp = reinterpret_cast<const f4*>(w    + (size_t)i0 * (KK * JJ));
        const f4* bp = reinterpret_cast<const f4*>(beta + (size_t)i0 * (KK * JJ));
#pragma unroll
        for (int q = 0; q < 6; ++q) { wv[q] = wp[q]; bb[q] = bp[q]; }
    }

    // Pin the load cluster above everything that follows.
    __builtin_amdgcn_sched_barrier(0);

    float ew[4][KK][JJ];
    float bt[4][KK][JJ];
#pragma unroll
    for (int u = 0; u < 4; ++u) {
#pragma unroll
        for (int k = 0; k < KK; ++k) {
#pragma unroll
            for (int j = 0; j < JJ; ++j) {
                const int idx = u * (KK * JJ) + k * JJ + j;  // compile-time after unroll
                ew[u][k][j] = __expf(reinterpret_cast<const float*>(wv)[idx]);
                bt[u][k][j] = reinterpret_cast<const float*>(bb)[idx];
            }
        }
    }

#pragma unroll
    for (int r = 0; r < ROWS; ++r) {
        f4 res;
#pragma unroll
        for (int u = 0; u < 4; ++u) {
            const float a = bv[r][u];
            float m0 = fmaf(a, ew[u][0][0], bt[u][0][0]);
            m0 = fmaxf(m0, fmaf(a, ew[u][0][1], bt[u][0][1]));
            m0 = fmaxf(m0, fmaf(a, ew[u][0][2], bt[u][0][2]));
            float m1 = fmaf(a, ew[u][1][0], bt[u][1][0]);
            m1 = fmaxf(m1, fmaf(a, ew[u][1][1], bt[u][1][1]));
            m1 = fmaxf(m1, fmaf(a, ew[u][1][2], bt[u][1][2]));
            res[u] = fminf(m0, m1);
        }
        *reinterpret_cast<f4*>(&out[base + (size_t)r * NB]) = res;
    }
}

extern "C" void kernel_launch(void* const* d_in, const int* in_sizes, int n_in,
                              void* d_out, int out_size, void* d_ws, size_t ws_size,
                              hipStream_t stream) {
    const float* bids = (const float*)d_in[0];   // [16384, 1024]
    const float* w    = (const float*)d_in[1];   // [1024, 2, 3]
    const float* beta = (const float*)d_in[2];   // [1024, 2, 3]
    float* out = (float*)d_out;                  // [16384, 1024]

    vvn_kernel<<<dim3(BATCH / ROWS), dim3(256), 0, stream>>>(bids, w, beta, out);
}

// Round 4
// 25.466 us; speedup vs baseline: 2.4602x; 1.1437x over previous
//
#include <hip/hip_runtime.h>

// VirtualValueNetwork: out[b,i] = min_k max_j (bids[b,i]*exp(w[i,k,j]) + beta[i,k,j])
// B=16384, N=1024, K=2, J=3.
// R5: R0's proven per-thread shape (2 buyers/thread, float2 rows, 8 rows per
// stripe, 8 waves/SIMD) + exact-fill persistent grid per Guideline 11:
// 2048 blocks = 256 CU x 8 blocks (max occupancy, one resident set, no
// turnover). Each block processes 2 stripes; params are loaded + exp'd ONCE
// (2x amortization) and the first stripe's HBM loads are issued BEFORE the
// param work so the 12 exps hide under stream latency.
// R2-R4 lessons: no nontemporal hints (breaks TCC servicing); float4/4-row at
// lower occupancy is slower (29.1 vs 25.0); keep VGPR <= 64 (R3 spilled).

typedef float f2 __attribute__((ext_vector_type(2)));
typedef float f4 __attribute__((ext_vector_type(4)));

#define NB    1024
#define BATCH 16384
#define ROWS  8
#define HALF  512
#define NSTRIPE 1024          // blocks per column-half; stripes 0..2047 total
// grid = 2048 blocks; block handles stripes s0 and s0+NSTRIPE.

__global__ __launch_bounds__(256, 8) void vvn_kernel(
    const float* __restrict__ bids,
    const float* __restrict__ w,
    const float* __restrict__ beta,
    float* __restrict__ out)
{
    const int t  = threadIdx.x;            // 0..255
    const int h  = blockIdx.x & 1;         // column half
    const int s0 = blockIdx.x >> 1;        // 0..1023
    const int i0 = h * HALF + (t << 1);    // 2 consecutive buyers

    const size_t baseA = (size_t)s0 * (ROWS * NB) + i0;

    // --- Issue stripe-0 row loads FIRST (the long-latency HBM stream) ---
    f2 bv[ROWS];
#pragma unroll
    for (int r = 0; r < ROWS; ++r)
        bv[r] = *reinterpret_cast<const f2*>(&bids[baseA + (size_t)r * NB]);

    // --- Params for 2 buyers (12+12 floats -> 24 VGPRs), exp'd while the
    //     row loads are in flight. Loaded once, reused for both stripes. ---
    float ew[2][2][3], bt[2][2][3];
    {
        const f4* wp = reinterpret_cast<const f4*>(w    + (size_t)i0 * 6);
        const f4* bp = reinterpret_cast<const f4*>(beta + (size_t)i0 * 6);
        f4 wv[3], bb[3];
#pragma unroll
        for (int q = 0; q < 3; ++q) { wv[q] = wp[q]; bb[q] = bp[q]; }
#pragma unroll
        for (int u = 0; u < 2; ++u)
#pragma unroll
            for (int k = 0; k < 2; ++k)
#pragma unroll
                for (int j = 0; j < 3; ++j) {
                    const int idx = u * 6 + k * 3 + j;   // compile-time
                    ew[u][k][j] = __expf(wv[idx >> 2][idx & 3]);
                    bt[u][k][j] = bb[idx >> 2][idx & 3];
                }
    }

    // --- Two stripes, same code; stripe 1 is +NSTRIPE stripes below. ---
#pragma unroll
    for (int it = 0; it < 2; ++it) {
        const size_t base = baseA + (size_t)it * ((size_t)NSTRIPE * ROWS * NB);
        if (it == 1) {
#pragma unroll
            for (int r = 0; r < ROWS; ++r)
                bv[r] = *reinterpret_cast<const f2*>(&bids[base + (size_t)r * NB]);
        }
#pragma unroll
        for (int r = 0; r < ROWS; ++r) {
            const float a0 = bv[r][0];
            const float a1 = bv[r][1];
            float m00 = fmaf(a0, ew[0][0][0], bt[0][0][0]);
            m00 = fmaxf(m00, fmaf(a0, ew[0][0][1], bt[0][0][1]));
            m00 = fmaxf(m00, fmaf(a0, ew[0][0][2], bt[0][0][2]));
            float m01 = fmaf(a0, ew[0][1][0], bt[0][1][0]);
            m01 = fmaxf(m01, fmaf(a0, ew[0][1][1], bt[0][1][1]));
            m01 = fmaxf(m01, fmaf(a0, ew[0][1][2], bt[0][1][2]));
            float m10 = fmaf(a1, ew[1][0][0], bt[1][0][0]);
            m10 = fmaxf(m10, fmaf(a1, ew[1][0][1], bt[1][0][1]));
            m10 = fmaxf(m10, fmaf(a1, ew[1][0][2], bt[1][0][2]));
            float m11 = fmaf(a1, ew[1][1][0], bt[1][1][0]);
            m11 = fmaxf(m11, fmaf(a1, ew[1][1][1], bt[1][1][1]));
            m11 = fmaxf(m11, fmaf(a1, ew[1][1][2], bt[1][1][2]));
            f2 res; res[0] = fminf(m00, m01); res[1] = fminf(m10, m11);
            *reinterpret_cast<f2*>(&out[base + (size_t)r * NB]) = res;
        }
    }
}

extern "C" void kernel_launch(void* const* d_in, const int* in_sizes, int n_in,
                              void* d_out, int out_size, void* d_ws, size_t ws_size,
                              hipStream_t stream) {
    const float* bids = (const float*)d_in[0];   // [16384, 1024]
    const float* w    = (const float*)d_in[1];   // [1024, 2, 3]
    const float* beta = (const float*)d_in[2];   // [1024, 2, 3]
    float* out = (float*)d_out;                  // [16384, 1024]

    vvn_kernel<<<dim3(2 * NSTRIPE), dim3(256), 0, stream>>>(bids, w, beta, out);
}